// Round 14
// baseline (71.270 us; speedup 1.0000x reference)
//
#include <hip/hip_runtime.h>
#include <math.h>

#define NL 4
#define NBATCH 16384
#define NS 5
#define ND 6
#define NH 2
#define NHD 3
#define NFF 2048
#define EPSV 1e-5f

#define ITEMS 16               // items per block -> grid 1024 -> 4 blocks/CU
#define TPB 256                // 4 waves, wave w = j-quarter jq
#define NPAIR 64               // jt-pairs (32 j's) per layer
#define ROW (NS * ND)          // 30
#define NVAL (ITEMS * ROW)     // 480

#define W1K_N (NL * NPAIR * 2 * 16)   // 8192 uint4
#define W2K_N (NL * NPAIR * 4 * 6)    // 6144 uint4

typedef __fp16 v8h __attribute__((ext_vector_type(8)));
typedef __fp16 v2h __attribute__((ext_vector_type(2)));
typedef float f32x4 __attribute__((ext_vector_type(4)));

union HU8 { uint4 u; v8h h; __fp16 f[8]; };

__device__ inline unsigned pk_u32(float a, float b) {
    union { v2h h; unsigned u; } x;
    x.h = __builtin_amdgcn_cvt_pkrtz(a, b);
    return x.u;
}
__device__ inline unsigned packh(float a, float b) {
    union { __fp16 h[2]; unsigned u; } x;
    x.h[0] = (__fp16)a; x.h[1] = (__fp16)b; return x.u;
}

// COMPACT prepacked A-fragments for v_mfma_f32_16x16x32_f16.
// Zero lanes are not stored: W1 frags live only in g==0 lanes (16/64);
// W2 frags only in rows r<6 (24/64 lanes). Exec-masked loads skip the rest.
// W1K[(l,p,t,r)]: j=(2p+t)*16+r -> {w01, w23, w45, {b1,0}}  (k-slots e=0..7)
// W2K[(l,p,g,r)]: 8 f16 over e: W2[r][j(g,e)], j = p*32 + (e<4?4g+e:16+4g+e-4)
__device__ __align__(16) uint4 W1K[W1K_N];
__device__ __align__(16) uint4 W2K[W2K_N + 64];  // pad: masked-lane addresses

__global__ void pack_kernel(const float* __restrict__ W1,
                            const float* __restrict__ b1,
                            const float* __restrict__ W2) {
    int idx = blockIdx.x * 256 + threadIdx.x;
    if (idx < W1K_N) {
        int r = idx & 15, t = (idx >> 4) & 1, p = (idx >> 5) & 63, l = idx >> 11;
        int j = (2 * p + t) * 16 + r;
        uint4 o;
        o.x = packh(W1[(size_t)(l * NFF + j) * ND + 0], W1[(size_t)(l * NFF + j) * ND + 1]);
        o.y = packh(W1[(size_t)(l * NFF + j) * ND + 2], W1[(size_t)(l * NFF + j) * ND + 3]);
        o.z = packh(W1[(size_t)(l * NFF + j) * ND + 4], W1[(size_t)(l * NFF + j) * ND + 5]);
        o.w = packh(b1[l * NFF + j], 0.f);
        W1K[idx] = o;
    } else if (idx < W1K_N + W2K_N) {
        int t = idx - W1K_N;
        int r = t % 6; int t6 = t / 6;
        int g = t6 & 3, p = (t6 >> 2) & 63, l = t6 >> 8;
        HU8 o;
#pragma unroll
        for (int e = 0; e < 8; ++e) {
            int j = p * 32 + ((e < 4) ? (4 * g + e) : (16 + 4 * g + e - 4));
            o.f[e] = (__fp16)W2[(size_t)(l * ND + r) * NFF + j];
        }
        W2K[t] = o.u;
    }
}

__global__ __launch_bounds__(TPB)
__attribute__((amdgpu_waves_per_eu(4, 4)))
void encoder_kernel(
    const float* __restrict__ xin,
    const float* __restrict__ Wq, const float* __restrict__ bq,
    const float* __restrict__ Wk, const float* __restrict__ bk,
    const float* __restrict__ Wv, const float* __restrict__ bv,
    const float* __restrict__ Wo, const float* __restrict__ bo,
    const float* __restrict__ b2,
    const float* __restrict__ g1, const float* __restrict__ be1,
    const float* __restrict__ g2, const float* __restrict__ be2,
    const float* __restrict__ Wfc, const float* __restrict__ bfc,
    float* __restrict__ out) {
    __shared__ float xs[NVAL];                 // 1.92 KB x state
    __shared__ float ybuf[4 * 5 * 32 * 4];     // 10.24 KB y frags (jq, mt, l32, 4)
    __shared__ float kvs[ITEMS * NS * 2 * ND]; // 3.84 KB k,v

    const int tid = threadIdx.x;
    const int base = blockIdx.x * ITEMS;

    if (tid < NVAL / 4)
        ((float4*)xs)[tid] = ((const float4*)(xin + (size_t)base * ROW))[tid];
    __syncthreads();

    const bool act = tid < ITEMS * NS;  // 80 attention threads: (item, token)
    const int ai = tid / NS;
    const int at = tid - ai * NS;

    // FFN wave role: wave = j-quarter jq; single 80-row M-panel (5 m-tiles)
    const int lane = tid & 63;
    const int jq = tid >> 6;
    const int c16 = lane & 15, g = lane >> 4;

    v8h z8; z8 = (v8h)(__fp16)0.f;
    const f32x4 cz = {0.f, 0.f, 0.f, 0.f};
    const uint4 u4z = make_uint4(0u, 0u, 0u, 0u);

    for (int l = 0; l < NL; ++l) {
        // weight base pointers for this wave's 16 pairs
        const uint4* p1 = W1K + (size_t)(l * NPAIR + jq * 16) * 32 + c16;
        const uint4* p2 = W2K + ((size_t)(l * NPAIR + jq * 16) * 4 + g) * 6 + c16;
        // preload BOTH buffers (pairs 0..3) before attention
        uint4 wa[2][2], wb[2][2], ww[2][2];
#pragma unroll
        for (int bb = 0; bb < 2; ++bb)
#pragma unroll
            for (int pp = 0; pp < 2; ++pp) {
                const int pr = bb * 2 + pp;
                wa[bb][pp] = u4z; wb[bb][pp] = u4z; ww[bb][pp] = u4z;
                if (g == 0) {
                    wa[bb][pp] = p1[pr * 32];
                    wb[bb][pp] = p1[pr * 32 + 16];
                }
                if (c16 < 6) ww[bb][pp] = p2[pr * 24];
            }

        // ---------------- attention: qkv ----------------
        float xr[ND], qv[ND];
        if (act) {
#pragma unroll
            for (int d = 0; d < ND; ++d) xr[d] = xs[(ai * NS + at) * ND + d];
#pragma unroll
            for (int d = 0; d < ND; ++d) {
                float aq = bq[l * ND + d], ak = bk[l * ND + d], av = bv[l * ND + d];
#pragma unroll
                for (int e = 0; e < ND; ++e) {
                    aq += Wq[(l * ND + d) * ND + e] * xr[e];
                    ak += Wk[(l * ND + d) * ND + e] * xr[e];
                    av += Wv[(l * ND + d) * ND + e] * xr[e];
                }
                qv[d] = aq;
                kvs[(ai * NS + at) * 2 * ND + d] = ak;
                kvs[(ai * NS + at) * 2 * ND + ND + d] = av;
            }
        }
        __syncthreads();
        // ---------------- attention: scores/ctx/outproj/LN1 ----------------
        if (act) {
            const float scale = 0.57735026919f;  // 1/sqrt(HD)
            float ctx[ND];
#pragma unroll
            for (int h = 0; h < NH; ++h) {
                float sc[NS];
                float mx = -1e30f;
#pragma unroll
                for (int u = 0; u < NS; ++u) {
                    float s = 0.f;
#pragma unroll
                    for (int d = 0; d < NHD; ++d)
                        s += qv[h * NHD + d] * kvs[(ai * NS + u) * 2 * ND + h * NHD + d];
                    s *= scale;
                    sc[u] = s;
                    mx = fmaxf(mx, s);
                }
                float sum = 0.f;
#pragma unroll
                for (int u = 0; u < NS; ++u) {
                    sc[u] = __expf(sc[u] - mx);
                    sum += sc[u];
                }
                float inv = 1.f / sum;
#pragma unroll
                for (int d = 0; d < NHD; ++d) {
                    float cx = 0.f;
#pragma unroll
                    for (int u = 0; u < NS; ++u)
                        cx += sc[u] * kvs[(ai * NS + u) * 2 * ND + ND + h * NHD + d];
                    ctx[h * NHD + d] = cx * inv;
                }
            }
            float yr[ND];
#pragma unroll
            for (int d = 0; d < ND; ++d) {
                float a = bo[l * ND + d];
#pragma unroll
                for (int e = 0; e < ND; ++e) a += Wo[(l * ND + d) * ND + e] * ctx[e];
                yr[d] = a + xr[d];
            }
            float m = 0.f;
#pragma unroll
            for (int d = 0; d < ND; ++d) m += yr[d];
            m *= (1.f / ND);
            float va = 0.f;
#pragma unroll
            for (int d = 0; d < ND; ++d) { float dv = yr[d] - m; va += dv * dv; }
            va *= (1.f / ND);
            float r = rsqrtf(va + EPSV);
#pragma unroll
            for (int d = 0; d < ND; ++d)
                xs[(ai * NS + at) * ND + d] =
                    (yr[d] - m) * r * g1[l * ND + d] + be1[l * ND + d];
        }
        __syncthreads();
        // ---------------- FFN: K=32 MFMA, pipelined compact weights ----------
        v8h xb[5];
#pragma unroll
        for (int mt = 0; mt < 5; ++mt) {
            HU8 ux; ux.u = u4z;
            if (g == 0) {
                int row = mt * 16 + c16;
                const float* xp = &xs[row * ND];
                ux.u.x = pk_u32(xp[0], xp[1]);
                ux.u.y = pk_u32(xp[2], xp[3]);
                ux.u.z = pk_u32(xp[4], xp[5]);
                ux.u.w = 0x00003c00u;   // f16 {1.0, 0.0} -> bias slot
            }
            xb[mt] = ux.h;
        }
        f32x4 y0 = cz, y1 = cz, y2 = cz, y3 = cz, y4 = cz;
        __builtin_amdgcn_s_setprio(1);
#pragma unroll
        for (int gq = 0; gq < 8; ++gq) {
            const int cur = gq & 1;
#pragma unroll
            for (int pp = 0; pp < 2; ++pp) {
                HU8 a1; a1.u = wa[cur][pp];
                HU8 b1f; b1f.u = wb[cur][pp];
                HU8 w2f; w2f.u = ww[cur][pp];
#define FFN_STEP(YREG, XB)                                                      \
                {                                                               \
                    f32x4 h0 = __builtin_amdgcn_mfma_f32_16x16x32_f16(          \
                        a1.h, (XB), cz, 0, 0, 0);                               \
                    f32x4 h1 = __builtin_amdgcn_mfma_f32_16x16x32_f16(          \
                        b1f.h, (XB), cz, 0, 0, 0);                              \
                    HU8 hb;                                                     \
                    hb.u.x = pk_u32(h0.x, h0.y);                                \
                    hb.u.y = pk_u32(h0.z, h0.w);                                \
                    hb.u.z = pk_u32(h1.x, h1.y);                                \
                    hb.u.w = pk_u32(h1.z, h1.w);                                \
                    hb.h = __builtin_elementwise_max(hb.h, z8);                 \
                    YREG = __builtin_amdgcn_mfma_f32_16x16x32_f16(              \
                        w2f.h, hb.h, YREG, 0, 0, 0);                            \
                }
                FFN_STEP(y0, xb[0])
                FFN_STEP(y1, xb[1])
                FFN_STEP(y2, xb[2])
                FFN_STEP(y3, xb[3])
                FFN_STEP(y4, xb[4])
#undef FFN_STEP
            }
            if (gq < 6) {   // refill the just-consumed buffer, 2 groups ahead
#pragma unroll
                for (int pp = 0; pp < 2; ++pp) {
                    const int pr = (gq + 2) * 2 + pp;
                    uint4 na = u4z, nb = u4z, nw = u4z;
                    if (g == 0) {
                        na = p1[pr * 32];
                        nb = p1[pr * 32 + 16];
                    }
                    if (c16 < 6) nw = p2[pr * 24];
                    wa[cur][pp] = na; wb[cur][pp] = nb; ww[cur][pp] = nw;
                }
            }
        }
        __builtin_amdgcn_s_setprio(0);
        // store C-frag rows 0..7 only (d<6): lanes < 32
        if (lane < 32) {
            f32x4* yb4 = (f32x4*)ybuf;
            int sb = (jq * 5) * 32 + lane;
            yb4[sb + 0 * 32] = y0;
            yb4[sb + 1 * 32] = y1;
            yb4[sb + 2 * 32] = y2;
            yb4[sb + 3 * 32] = y3;
            yb4[sb + 4 * 32] = y4;
        }
        __syncthreads();
        // ---------------- residual + LN2 (reduce the 4 j-quarters) ----------
        if (act) {
            int R = ai * NS + at;            // block row 0..79
            int mtR = R >> 4, cR = R & 15;
            float yr[ND];
#pragma unroll
            for (int d = 0; d < ND; ++d) {
                int gR = d >> 2, iR = d & 3;
                float s = 0.f;
#pragma unroll
                for (int q = 0; q < 4; ++q)
                    s += ybuf[((q * 5 + mtR) * 32 + gR * 16 + cR) * 4 + iR];
                yr[d] = xs[R * ND + d] + s + b2[l * ND + d];
            }
            float m = 0.f;
#pragma unroll
            for (int d = 0; d < ND; ++d) m += yr[d];
            m *= (1.f / ND);
            float va = 0.f;
#pragma unroll
            for (int d = 0; d < ND; ++d) { float dv = yr[d] - m; va += dv * dv; }
            va *= (1.f / ND);
            float r = rsqrtf(va + EPSV);
#pragma unroll
            for (int d = 0; d < ND; ++d)
                xs[R * ND + d] = (yr[d] - m) * r * g2[l * ND + d] + be2[l * ND + d];
        }
        __syncthreads();
    }
    // ---------------- classification head + softmax ----------------
    if (tid < ITEMS) {
        float l0 = bfc[0], l1 = bfc[1];
#pragma unroll
        for (int v = 0; v < ROW; ++v) {
            float xv = xs[tid * ROW + v];
            l0 += Wfc[v] * xv;
            l1 += Wfc[ROW + v] * xv;
        }
        float mx = fmaxf(l0, l1);
        float e0 = __expf(l0 - mx), e1 = __expf(l1 - mx);
        float inv = 1.f / (e0 + e1);
        out[(size_t)(base + tid) * 2 + 0] = e0 * inv;
        out[(size_t)(base + tid) * 2 + 1] = e1 * inv;
    }
}

extern "C" void kernel_launch(void* const* d_in, const int* in_sizes, int n_in,
                              void* d_out, int out_size, void* d_ws, size_t ws_size,
                              hipStream_t stream) {
    (void)in_sizes; (void)n_in; (void)d_ws; (void)ws_size; (void)out_size;
    const float* x = (const float*)d_in[0];
    const float* Wq = (const float*)d_in[1];
    const float* bq = (const float*)d_in[2];
    const float* Wk = (const float*)d_in[3];
    const float* bk = (const float*)d_in[4];
    const float* Wv = (const float*)d_in[5];
    const float* bv = (const float*)d_in[6];
    const float* Wo = (const float*)d_in[7];
    const float* bo = (const float*)d_in[8];
    const float* W1 = (const float*)d_in[9];
    const float* b1 = (const float*)d_in[10];
    const float* W2 = (const float*)d_in[11];
    const float* b2 = (const float*)d_in[12];
    const float* g1 = (const float*)d_in[13];
    const float* be1 = (const float*)d_in[14];
    const float* g2 = (const float*)d_in[15];
    const float* be2 = (const float*)d_in[16];
    const float* Wfc = (const float*)d_in[17];
    const float* bfc = (const float*)d_in[18];
    float* out = (float*)d_out;

    const int npack = W1K_N + W2K_N;  // 14336
    hipLaunchKernelGGL(pack_kernel, dim3((npack + 255) / 256), dim3(256), 0, stream,
                       W1, b1, W2);
    hipLaunchKernelGGL(encoder_kernel, dim3(NBATCH / ITEMS), dim3(TPB), 0, stream,
                       x, Wq, bq, Wk, bk, Wv, bv, Wo, bo, b2, g1, be1, g2, be2,
                       Wfc, bfc, out);
}